// Round 12
// baseline (192.400 us; speedup 1.0000x reference)
//
#include <hip/hip_runtime.h>

typedef __attribute__((ext_vector_type(8))) __bf16 bfrag;
typedef __attribute__((ext_vector_type(4))) float f32x4;

#define MFMA(a, b, c) __builtin_amdgcn_mfma_f32_16x16x32_bf16((a), (b), (c), 0, 0, 0)

#define D_MODEL 1024
#define SEQ     2048
#define NB      2
#define NH      16
#define HD      64
#define MROWS   (NB * SEQ)   // 4096

#define SCALE_LOG2 0.18033688011112043f   // log2(e)/sqrt(HD), folded into Q
#define NEG_BIG    (-3.0e38f)

#define GLOBAL_AS(p) ((const __attribute__((address_space(1))) void*)(p))
#define LDS_AS(p)    ((__attribute__((address_space(3))) void*)(p))
#define ASYNC_CP16(g, l) __builtin_amdgcn_global_load_lds(GLOBAL_AS(g), LDS_AS(l), 16, 0, 0)

// ---------------------------------------------------------------------------
// Prep: z<4 -> transpose weight z fp32 [K][N] -> bf16 [N][K]; z==4 -> x cvt.
// (R7: float4 transpose loads)
// ---------------------------------------------------------------------------
__global__ __launch_bounds__(256) void k_prep(
    const float* __restrict__ x,
    const float* __restrict__ Wq, const float* __restrict__ Wk,
    const float* __restrict__ Wv, const float* __restrict__ Wo,
    __bf16* __restrict__ Wt, __bf16* __restrict__ xb)
{
    __shared__ __bf16 t[64][65];
    if (blockIdx.z == 4) {
        size_t base = ((size_t)(blockIdx.y * 16 + blockIdx.x)) * 16384;
        for (int j = 0; j < 8; ++j) {
            size_t i = base + (size_t)j * 2048 + (size_t)threadIdx.x * 8;
            float4 f0 = *(const float4*)&x[i];
            float4 f1 = *(const float4*)&x[i + 4];
            union { uint4 u; __bf16 h[8]; } cv;
            cv.h[0] = (__bf16)f0.x; cv.h[1] = (__bf16)f0.y;
            cv.h[2] = (__bf16)f0.z; cv.h[3] = (__bf16)f0.w;
            cv.h[4] = (__bf16)f1.x; cv.h[5] = (__bf16)f1.y;
            cv.h[6] = (__bf16)f1.z; cv.h[7] = (__bf16)f1.w;
            *(uint4*)&xb[i] = cv.u;
        }
        return;
    }
    const float* src = (blockIdx.z == 0) ? Wq : (blockIdx.z == 1) ? Wk
                      : (blockIdx.z == 2) ? Wv : Wo;
    __bf16* dst = Wt + (size_t)blockIdx.z * (1024u * 1024u);
    int tr = blockIdx.y * 64, tc = blockIdx.x * 64;
    for (int j = 0; j < 4; ++j) {
        int id = threadIdx.x + j * 256;          // 0..1023
        int r = id >> 4;                         // 0..63
        int c4 = (id & 15) * 4;                  // 0,4,..,60
        float4 f = *(const float4*)&src[(size_t)(tr + r) * 1024 + tc + c4];
        t[r][c4 + 0] = (__bf16)f.x; t[r][c4 + 1] = (__bf16)f.y;
        t[r][c4 + 2] = (__bf16)f.z; t[r][c4 + 3] = (__bf16)f.w;
    }
    __syncthreads();
    for (int j = 0; j < 2; ++j) {
        int id = threadIdx.x + j * 256;          // 0..511
        int r = id >> 3;                         // out row 0..63
        int c8 = (id & 7) * 8;                   // col group
        union { uint4 u; __bf16 h[8]; } pk;
        for (int i = 0; i < 8; ++i) pk.h[i] = t[c8 + i][r];
        *(uint4*)&dst[(size_t)(tc + r) * 1024 + tr + c8] = pk.u;
    }
}

// ---------------------------------------------------------------------------
// 128x128 GEMM: Y[4096][1024] = A * W + bias.  (R7: XCD-chunked swizzle)
// ---------------------------------------------------------------------------
template <int MODE, bool WT>
__global__ __launch_bounds__(256) void k_gemm128(
    const void* __restrict__ Ap,
    const void* __restrict__ W0, const void* __restrict__ W1,
    const void* __restrict__ W2,
    const float* __restrict__ b0, const float* __restrict__ b1,
    const float* __restrict__ b2, void* __restrict__ dstp)
{
    constexpr int AST = WT ? 64 : 72;
    alignas(16) __shared__ __bf16 SH[18432];   // 36 KB: staging + C restage
    __bf16* As = SH;
    __bf16* Bs = SH + 128 * AST;

    const int tid = threadIdx.x;
    const int z = blockIdx.z;
    const int lid = blockIdx.x + (blockIdx.y << 3);      // 0..255
    const int mt = ((lid & 7) << 2) + ((lid >> 3) >> 3); // XCD-chunked m
    const int nt = (lid >> 3) & 7;
    const int m0 = mt * 128;
    const int n0 = nt * 128;
    const void* W     = (z == 0) ? W0 : (z == 1) ? W1 : W2;
    const float* bias = (z == 0) ? b0 : (z == 1) ? b1 : b2;

    const int wid = tid >> 6, lane = tid & 63;
    const int quad = lane >> 4, l16 = lane & 15;
    const int wRow = (wid >> 1) * 64, wCol = (wid & 1) * 64;

    f32x4 acc[4][4];
    const f32x4 zero = {0.f, 0.f, 0.f, 0.f};
    for (int mi = 0; mi < 4; ++mi)
        for (int ni = 0; ni < 4; ++ni) acc[mi][ni] = zero;

    const int srow = tid >> 3;
    const int sseg = (tid & 7) * 8;
    const int bkrow = tid >> 4;
    const int bnseg = (tid & 15) * 8;
    const int arow = lane >> 3;
    const int akoff = ((lane & 7) * 8) ^ (arow * 8);
    const int sw = (l16 & 7) * 8;

    for (int k0 = 0; k0 < D_MODEL; k0 += 64) {
        __syncthreads();
        if (WT) {
            const __bf16* Ab = (const __bf16*)Ap;
            const __bf16* Bt = (const __bf16*)W;
            for (int it = 0; it < 4; ++it) {
                int row = wid * 32 + it * 8;
                ASYNC_CP16(&Ab[(size_t)(m0 + row + arow) * D_MODEL + k0 + akoff],
                           &As[row * 64]);
                ASYNC_CP16(&Bt[(size_t)(n0 + row + arow) * D_MODEL + k0 + akoff],
                           &Bs[row * 64]);
            }
        } else {
            if (MODE == 0) {
                const float* A = (const float*)Ap;
                for (int it = 0; it < 4; ++it) {
                    int row = srow + it * 32;
                    const float* src = &A[(size_t)(m0 + row) * D_MODEL + k0 + sseg];
                    float4 f0 = *(const float4*)src;
                    float4 f1 = *(const float4*)(src + 4);
                    union { uint4 u; __bf16 h[8]; } cv;
                    cv.h[0] = (__bf16)f0.x; cv.h[1] = (__bf16)f0.y;
                    cv.h[2] = (__bf16)f0.z; cv.h[3] = (__bf16)f0.w;
                    cv.h[4] = (__bf16)f1.x; cv.h[5] = (__bf16)f1.y;
                    cv.h[6] = (__bf16)f1.z; cv.h[7] = (__bf16)f1.w;
                    *(uint4*)&As[row * AST + sseg] = cv.u;
                }
            } else {
                const __bf16* A = (const __bf16*)Ap;
                for (int it = 0; it < 4; ++it) {
                    int row = srow + it * 32;
                    uint4 va = *(const uint4*)&A[(size_t)(m0 + row) * D_MODEL + k0 + sseg];
                    *(uint4*)&As[row * AST + sseg] = va;
                }
            }
            const float* Wf = (const float*)W;
            for (int it = 0; it < 4; ++it) {
                int krow = bkrow + it * 16;
                const float* src = &Wf[(size_t)(k0 + krow) * D_MODEL + n0 + bnseg];
                float4 f0 = *(const float4*)src;
                float4 f1 = *(const float4*)(src + 4);
                Bs[(bnseg + 0) * AST + krow] = (__bf16)f0.x;
                Bs[(bnseg + 1) * AST + krow] = (__bf16)f0.y;
                Bs[(bnseg + 2) * AST + krow] = (__bf16)f0.z;
                Bs[(bnseg + 3) * AST + krow] = (__bf16)f0.w;
                Bs[(bnseg + 4) * AST + krow] = (__bf16)f1.x;
                Bs[(bnseg + 5) * AST + krow] = (__bf16)f1.y;
                Bs[(bnseg + 6) * AST + krow] = (__bf16)f1.z;
                Bs[(bnseg + 7) * AST + krow] = (__bf16)f1.w;
            }
        }
        __syncthreads();
        for (int kk = 0; kk < 64; kk += 32) {
            bfrag af[4], bf[4];
            if (WT) {
                int ko = (kk + quad * 8) ^ sw;
                for (int mi = 0; mi < 4; ++mi)
                    af[mi] = *(const bfrag*)&As[(wRow + mi * 16 + l16) * 64 + ko];
                for (int ni = 0; ni < 4; ++ni)
                    bf[ni] = *(const bfrag*)&Bs[(wCol + ni * 16 + l16) * 64 + ko];
            } else {
                for (int mi = 0; mi < 4; ++mi)
                    af[mi] = *(const bfrag*)&As[(wRow + mi * 16 + l16) * AST + kk + quad * 8];
                for (int ni = 0; ni < 4; ++ni)
                    bf[ni] = *(const bfrag*)&Bs[(wCol + ni * 16 + l16) * AST + kk + quad * 8];
            }
            for (int mi = 0; mi < 4; ++mi)
                for (int ni = 0; ni < 4; ++ni)
                    acc[mi][ni] = MFMA(af[mi], bf[ni], acc[mi][ni]);
        }
    }

    if (MODE == 0) {
        float biasv[4];
        for (int ni = 0; ni < 4; ++ni) biasv[ni] = bias[n0 + wCol + ni * 16 + l16];
        const int b = m0 >> 11, m0s = m0 & 2047, h0 = n0 >> 6;
        __syncthreads();
        if (z < 2) {
            for (int mi = 0; mi < 4; ++mi)
                for (int ni = 0; ni < 4; ++ni) {
                    int col = wCol + ni * 16 + l16;
                    for (int r = 0; r < 4; ++r) {
                        float v = acc[mi][ni][r] + biasv[ni];
                        if (z == 0) v *= SCALE_LOG2;
                        SH[(wRow + mi * 16 + quad * 4 + r) * 136 + col] = (__bf16)v;
                    }
                }
            __syncthreads();
            __bf16* qk = (__bf16*)dstp + (size_t)z * (MROWS * (size_t)D_MODEL);
            for (int i = 0; i < 8; ++i) {
                int rid = i * 32 + (tid >> 3);
                int hl = rid >> 7, sl = rid & 127;
                int dcol = (tid & 7) * 8;
                uint4 v = *(const uint4*)&SH[sl * 136 + hl * 64 + dcol];
                *(uint4*)&qk[(((size_t)b * NH + h0 + hl) * SEQ + m0s + sl) * HD + dcol] = v;
            }
        } else {
            for (int mi = 0; mi < 4; ++mi)
                for (int ni = 0; ni < 4; ++ni) {
                    int col = wCol + ni * 16 + l16;
                    int s0 = wRow + mi * 16 + quad * 4;
                    union { unsigned long long u; __bf16 h4[4]; } pk;
                    for (int r = 0; r < 4; ++r)
                        pk.h4[r] = (__bf16)(acc[mi][ni][r] + biasv[ni]);
                    *(unsigned long long*)&SH[col * 136 + s0] = pk.u;
                }
            __syncthreads();
            __bf16* vv = (__bf16*)dstp + (size_t)2 * (MROWS * (size_t)D_MODEL);
            for (int i = 0; i < 8; ++i) {
                int rid = i * 16 + (tid >> 4);
                int hl = rid >> 6, d = rid & 63;
                int sc = (tid & 15) * 8;
                uint4 v = *(const uint4*)&SH[rid * 136 + sc];
                *(uint4*)&vv[(((size_t)b * NH + h0 + hl) * HD + d) * SEQ + m0s + sc] = v;
            }
        }
    } else {
        for (int mi = 0; mi < 4; ++mi)
            for (int ni = 0; ni < 4; ++ni) {
                int gn = n0 + wCol + ni * 16 + l16;
                float bv = bias[gn];
                for (int r = 0; r < 4; ++r) {
                    int gm = m0 + wRow + mi * 16 + quad * 4 + r;
                    ((float*)dstp)[(size_t)gm * D_MODEL + gn] = acc[mi][ni][r] + bv;
                }
            }
    }
}

// ---------------------------------------------------------------------------
// Output GEMM (round-0 proven): Y[4096][1024] fp32 = A(bf16)*WoT(bf16)+bo.
// 64(M)x128(N) tiles -> grid (8,64), 512 blocks (2/CU). (R7: XCD swizzle)
// ---------------------------------------------------------------------------
__global__ __launch_bounds__(256) void k_gemm_out(
    const __bf16* __restrict__ A, const __bf16* __restrict__ Bt,
    const float* __restrict__ bias, float* __restrict__ dst)
{
    alignas(16) __shared__ __bf16 As[64 * 64];    // 8 KB
    alignas(16) __shared__ __bf16 Bs[128 * 64];   // 16 KB

    const int tid = threadIdx.x;
    const int lid = blockIdx.x + (blockIdx.y << 3);      // 0..511
    const int mt = ((lid & 7) << 3) + ((lid >> 3) >> 3); // XCD-chunked m
    const int nt = (lid >> 3) & 7;
    const int m0 = mt * 64;
    const int n0 = nt * 128;
    const int wid = tid >> 6, lane = tid & 63;
    const int quad = lane >> 4, l16 = lane & 15;
    const int wRow = (wid >> 1) * 32, wCol = (wid & 1) * 64;

    f32x4 acc[2][4];
    const f32x4 zero = {0.f, 0.f, 0.f, 0.f};
    for (int mi = 0; mi < 2; ++mi)
        for (int ni = 0; ni < 4; ++ni) acc[mi][ni] = zero;

    const int arow = lane >> 3;
    const int akoff = ((lane & 7) * 8) ^ (arow * 8);
    const int sw = (l16 & 7) * 8;

    for (int k0 = 0; k0 < D_MODEL; k0 += 64) {
        __syncthreads();
        for (int it = 0; it < 2; ++it) {
            int row = wid * 16 + it * 8;
            ASYNC_CP16(&A[(size_t)(m0 + row + arow) * D_MODEL + k0 + akoff],
                       &As[row * 64]);
        }
        for (int it = 0; it < 4; ++it) {
            int row = wid * 32 + it * 8;
            ASYNC_CP16(&Bt[(size_t)(n0 + row + arow) * D_MODEL + k0 + akoff],
                       &Bs[row * 64]);
        }
        __syncthreads();
        for (int kk = 0; kk < 64; kk += 32) {
            int ko = (kk + quad * 8) ^ sw;
            bfrag af[2], bf[4];
            for (int mi = 0; mi < 2; ++mi)
                af[mi] = *(const bfrag*)&As[(wRow + mi * 16 + l16) * 64 + ko];
            for (int ni = 0; ni < 4; ++ni)
                bf[ni] = *(const bfrag*)&Bs[(wCol + ni * 16 + l16) * 64 + ko];
            for (int mi = 0; mi < 2; ++mi)
                for (int ni = 0; ni < 4; ++ni)
                    acc[mi][ni] = MFMA(af[mi], bf[ni], acc[mi][ni]);
        }
    }

    for (int mi = 0; mi < 2; ++mi)
        for (int ni = 0; ni < 4; ++ni) {
            int gn = n0 + wCol + ni * 16 + l16;
            float bv = bias[gn];
            for (int r = 0; r < 4; ++r) {
                int gm = m0 + wRow + mi * 16 + quad * 4 + r;
                dst[(size_t)gm * D_MODEL + gn] = acc[mi][ni][r] + bv;
            }
        }
}

// ---------------------------------------------------------------------------
// Flash attention (causal), S^T formulation, v12: FUSED BALANCED PAIRS.
//   v11 merged pair (qbA = 31-u, qbB = u) into one key-pass but ran A and B
//   serially per tile. v12 fuses the overlap region (t < ntB):
//     - K-frags loaded ONCE, feed both stA and stB        (-8 b128/tile)
//     - pack A->Ps, B->Ps2; ONE lgkmcnt(0) instead of two (-1 drain/tile)
//     - V-frags loaded ONCE, feed both oA and oB          (-8 b128/tile)
//   A needs no mask in the overlap region (t < ntB <= 16 <= qbA = ntA-1
//   for all u in [0,15]). Non-overlap region keeps the A-only body verbatim.
//   LDS 32.8 KB (grid-bound occupancy: 512 blocks = 2/CU). All register
//   arrays constant-indexed (rule #20). ones-trick denominator kept.
// ---------------------------------------------------------------------------
__global__ __launch_bounds__(256) void k_attn(
    const __bf16* __restrict__ Q, const __bf16* __restrict__ K,
    const __bf16* __restrict__ Vt, __bf16* __restrict__ O)
{
    alignas(16) __shared__ __bf16 Ks[64 * 64];      // 8 KB, swizzled
    alignas(16) __shared__ __bf16 Vts[64 * 64];     // 8 KB, swizzled [d][key]
    alignas(16) __shared__ __bf16 Ps[4][16 * 64];   // 8 KB, P^T (pass A)
    alignas(16) __shared__ __bf16 Ps2[4][16 * 64];  // 8 KB, P^T (pass B)

    const int tid = threadIdx.x, wid = tid >> 6, lane = tid & 63;
    const int quad = lane >> 4, l16 = lane & 15;
    const int u = (blockIdx.x + blockIdx.y + blockIdx.z) & 15;  // 0..15
    const int h = blockIdx.y, b = blockIdx.z;
    const int qbA = 31 - u, qbB = u;               // pair: long + short
    const size_t bh = ((size_t)b * NH + h) * SEQ * HD;
    const __bf16* Kg  = K + bh;
    const __bf16* Vtg = Vt + ((size_t)b * NH + h) * HD * SEQ;  // [d][s]

    const __bf16* QgA = Q + bh + (size_t)qbA * 64 * HD;
    const __bf16* QgB = Q + bh + (size_t)qbB * 64 * HD;
    bfrag qfA0 = *(const bfrag*)&QgA[(size_t)(wid * 16 + l16) * HD + quad * 8];
    bfrag qfA1 = *(const bfrag*)&QgA[(size_t)(wid * 16 + l16) * HD + 32 + quad * 8];
    bfrag qfB0 = *(const bfrag*)&QgB[(size_t)(wid * 16 + l16) * HD + quad * 8];
    bfrag qfB1 = *(const bfrag*)&QgB[(size_t)(wid * 16 + l16) * HD + 32 + quad * 8];

    // constant all-ones B-fragment for the denominator MFMA
    union { uint4 u; bfrag f; } onesu;
    onesu.u = make_uint4(0x3F803F80u, 0x3F803F80u, 0x3F803F80u, 0x3F803F80u);
    const bfrag onesf = onesu.f;

    const f32x4 zero = {0.f, 0.f, 0.f, 0.f};
    f32x4 oA[4], oB[4];
    for (int dt = 0; dt < 4; ++dt) { oA[dt] = zero; oB[dt] = zero; }
    f32x4 o_lA = zero, o_lB = zero;                // row-sum accumulators
    const int qA = qbA * 64 + wid * 16 + l16;
    const int qB = qbB * 64 + wid * 16 + l16;
    const int ntA = qbA + 1, ntB = qbB + 1;        // ntB <= 16 < ntA
    const int sw = (l16 & 7) * 8;

    const int row0 = tid >> 3, seg = (tid & 7) * 8;
    const int sseg = seg ^ ((row0 & 7) * 8);       // swizzled dest k-offset

    const __bf16* Kr0 = &Kg[(size_t)row0 * HD + seg];
    const __bf16* Kr1 = &Kg[(size_t)(row0 + 32) * HD + seg];
    const __bf16* Vr0 = &Vtg[(size_t)row0 * SEQ + seg];
    const __bf16* Vr1 = &Vtg[(size_t)(row0 + 32) * SEQ + seg];

    uint4 kreg0 = *(const uint4*)(Kr0);
    uint4 kreg1 = *(const uint4*)(Kr1);
    uint4 vreg0 = *(const uint4*)(Vr0);
    uint4 vreg1 = *(const uint4*)(Vr1);

    for (int t = 0; t < ntA; ++t) {
        const int j0 = t * 64;
        __syncthreads();
        *(uint4*)&Ks[row0 * 64 + sseg] = kreg0;
        *(uint4*)&Ks[(row0 + 32) * 64 + sseg] = kreg1;
        *(uint4*)&Vts[row0 * 64 + sseg] = vreg0;
        *(uint4*)&Vts[(row0 + 32) * 64 + sseg] = vreg1;
        if (t + 1 < ntA) {
            const size_t j1k = (size_t)(j0 + 64) * HD;
            const int j1v = j0 + 64;
            kreg0 = *(const uint4*)(Kr0 + j1k);
            kreg1 = *(const uint4*)(Kr1 + j1k);
            vreg0 = *(const uint4*)(Vr0 + j1v);
            vreg1 = *(const uint4*)(Vr1 + j1v);
        }
        __syncthreads();

        if (t < ntB) {
            // ---- fused A+B tile: shared K/V frags, one LDS drain ----
            f32x4 stA[4], stB[4];
            for (int kt = 0; kt < 4; ++kt) {
                bfrag ka0 = *(const bfrag*)&Ks[(kt * 16 + l16) * 64 + ((quad * 8) ^ sw)];
                bfrag ka1 = *(const bfrag*)&Ks[(kt * 16 + l16) * 64 + ((32 + quad * 8) ^ sw)];
                stA[kt] = MFMA(ka1, qfA1, MFMA(ka0, qfA0, zero));
                stB[kt] = MFMA(ka1, qfB1, MFMA(ka0, qfB0, zero));
            }

            // A never masked here (t < ntB <= 16 <= qbA = ntA-1)
            for (int kt = 0; kt < 4; ++kt)
                for (int r = 0; r < 4; ++r)
                    stA[kt][r] = exp2f(stA[kt][r]);

            if (t == ntB - 1) {
                for (int kt = 0; kt < 4; ++kt)
                    for (int r = 0; r < 4; ++r) {
                        float v = (j0 + kt * 16 + quad * 4 + r > qB) ? NEG_BIG : stB[kt][r];
                        stB[kt][r] = exp2f(v);
                    }
            } else {
                for (int kt = 0; kt < 4; ++kt)
                    for (int r = 0; r < 4; ++r)
                        stB[kt][r] = exp2f(stB[kt][r]);
            }

            for (int kt = 0; kt < 4; ++kt) {
                union { unsigned long long u; __bf16 h4[4]; } pkA;
                union { unsigned long long u; __bf16 h4[4]; } pkB;
                for (int r = 0; r < 4; ++r) { pkA.h4[r] = (__bf16)stA[kt][r];
                                              pkB.h4[r] = (__bf16)stB[kt][r]; }
                const int po = l16 * 64 + ((kt * 16 + quad * 4) ^ sw);
                *(unsigned long long*)&Ps[wid][po]  = pkA.u;
                *(unsigned long long*)&Ps2[wid][po] = pkB.u;
            }
            asm volatile("s_waitcnt lgkmcnt(0)" ::: "memory");

            for (int c = 0; c < 2; ++c) {
                int ko = (c * 32 + quad * 8) ^ sw;
                bfrag pfA = *(const bfrag*)&Ps[wid][l16 * 64 + ko];
                bfrag pfB = *(const bfrag*)&Ps2[wid][l16 * 64 + ko];
                for (int dt = 0; dt < 4; ++dt) {
                    bfrag vf = *(const bfrag*)&Vts[(dt * 16 + l16) * 64 + ko];
                    oA[dt] = MFMA(pfA, vf, oA[dt]);
                    oB[dt] = MFMA(pfB, vf, oB[dt]);
                }
                o_lA = MFMA(pfA, onesf, o_lA);
                o_lB = MFMA(pfB, onesf, o_lB);
            }
        } else {
            // ---- A-only tile (proven body) ----
            f32x4 st[4];
            for (int kt = 0; kt < 4; ++kt) {
                bfrag ka0 = *(const bfrag*)&Ks[(kt * 16 + l16) * 64 + ((quad * 8) ^ sw)];
                bfrag ka1 = *(const bfrag*)&Ks[(kt * 16 + l16) * 64 + ((32 + quad * 8) ^ sw)];
                st[kt] = MFMA(ka1, qfA1, MFMA(ka0, qfA0, zero));
            }

            if (t == ntA - 1) {
                for (int kt = 0; kt < 4; ++kt)
                    for (int r = 0; r < 4; ++r) {
                        float v = (j0 + kt * 16 + quad * 4 + r > qA) ? NEG_BIG : st[kt][r];
                        st[kt][r] = exp2f(v);
                    }
            } else {
                for (int kt = 0; kt < 4; ++kt)
                    for (int r = 0; r < 4; ++r)
                        st[kt][r] = exp2f(st[kt][r]);
            }

            for (int kt = 0; kt < 4; ++kt) {
                union { unsigned long long u; __bf16 h4[4]; } pk;
                for (int r = 0; r < 4; ++r) pk.h4[r] = (__bf16)st[kt][r];
                *(unsigned long long*)&Ps[wid][l16 * 64 + ((kt * 16 + quad * 4) ^ sw)] = pk.u;
            }
            asm volatile("s_waitcnt lgkmcnt(0)" ::: "memory");

            for (int c = 0; c < 2; ++c) {
                int ko = (c * 32 + quad * 8) ^ sw;
                bfrag pf = *(const bfrag*)&Ps[wid][l16 * 64 + ko];
                for (int dt = 0; dt < 4; ++dt) {
                    bfrag vf = *(const bfrag*)&Vts[(dt * 16 + l16) * 64 + ko];
                    oA[dt] = MFMA(pf, vf, oA[dt]);
                }
                o_lA = MFMA(pf, onesf, o_lA);
            }
        }
    }

    // epilogues: normalize by row-sums, write O for both q-blocks
    for (int r = 0; r < 4; ++r) {
        float inv = 1.0f / o_lA[r];
        size_t base = ((size_t)b * SEQ + qbA * 64 + wid * 16 + quad * 4 + r) * D_MODEL
                    + (size_t)h * HD;
        for (int dt = 0; dt < 4; ++dt)
            O[base + dt * 16 + l16] = (__bf16)(oA[dt][r] * inv);
    }
    for (int r = 0; r < 4; ++r) {
        float inv = 1.0f / o_lB[r];
        size_t base = ((size_t)b * SEQ + qbB * 64 + wid * 16 + quad * 4 + r) * D_MODEL
                    + (size_t)h * HD;
        for (int dt = 0; dt < 4; ++dt)
            O[base + dt * 16 + l16] = (__bf16)(oB[dt][r] * inv);
    }
}

// ---------------------------------------------------------------------------
extern "C" void kernel_launch(void* const* d_in, const int* in_sizes, int n_in,
                              void* d_out, int out_size, void* d_ws, size_t ws_size,
                              hipStream_t stream)
{
    const float* x  = (const float*)d_in[0];
    const float* Wq = (const float*)d_in[1];
    const float* bq = (const float*)d_in[2];
    const float* Wk = (const float*)d_in[3];
    const float* bk = (const float*)d_in[4];
    const float* Wv = (const float*)d_in[5];
    const float* bv = (const float*)d_in[6];
    const float* Wo = (const float*)d_in[7];
    const float* bo = (const float*)d_in[8];

    __bf16* ws = (__bf16*)d_ws;
    const size_t M1 = 1024u * 1024u;
    __bf16* qkv    = ws;                      // Q @0, K @4M, Vt @8M (24 MB)
    __bf16* attn_o = ws + 12 * M1;            // 4M (8 MB)
    __bf16* Wt     = ws + 16 * M1;            // 4M (8 MB)
    __bf16* xb     = ws + 20 * M1;            // 4M (8 MB) -> 48 MB total

    const bool fast = ws_size >= (size_t)48 * 1024 * 1024;

    if (fast) {
        k_prep<<<dim3(16, 16, 5), 256, 0, stream>>>(x, Wq, Wk, Wv, Wo, Wt, xb);
        k_gemm128<0, true><<<dim3(8, 32, 3), 256, 0, stream>>>(
            xb, Wt, Wt + M1, Wt + 2 * M1, bq, bk, bv, qkv);
        k_attn<<<dim3(16, 16, 2), 256, 0, stream>>>(
            qkv, qkv + 4 * M1, qkv + 8 * M1, attn_o);
        k_gemm_out<<<dim3(8, 64), 256, 0, stream>>>(
            attn_o, Wt + 3 * M1, bo, (float*)d_out);
    } else {
        k_gemm128<0, false><<<dim3(8, 32, 3), 256, 0, stream>>>(
            x, Wq, Wk, Wv, bq, bk, bv, qkv);
        k_attn<<<dim3(16, 16, 2), 256, 0, stream>>>(
            qkv, qkv + 4 * M1, qkv + 8 * M1, attn_o);
        k_gemm128<1, false><<<dim3(8, 32, 1), 256, 0, stream>>>(
            attn_o, Wo, Wo, Wo, bo, bo, bo, (float*)d_out);
    }
}

// Round 13
// 187.637 us; speedup vs baseline: 1.0254x; 1.0254x over previous
//
#include <hip/hip_runtime.h>

typedef __attribute__((ext_vector_type(8))) __bf16 bfrag;
typedef __attribute__((ext_vector_type(4))) float f32x4;

#define MFMA(a, b, c) __builtin_amdgcn_mfma_f32_16x16x32_bf16((a), (b), (c), 0, 0, 0)

#define D_MODEL 1024
#define SEQ     2048
#define NB      2
#define NH      16
#define HD      64
#define MROWS   (NB * SEQ)   // 4096

#define SCALE_LOG2 0.18033688011112043f   // log2(e)/sqrt(HD), folded into Q
#define NEG_BIG    (-3.0e38f)

#define GLOBAL_AS(p) ((const __attribute__((address_space(1))) void*)(p))
#define LDS_AS(p)    ((__attribute__((address_space(3))) void*)(p))
#define ASYNC_CP16(g, l) __builtin_amdgcn_global_load_lds(GLOBAL_AS(g), LDS_AS(l), 16, 0, 0)

// ---------------------------------------------------------------------------
// Prep: z<4 -> transpose weight z fp32 [K][N] -> bf16 [N][K]; z==4 -> x cvt.
// (R7: float4 transpose loads)
// ---------------------------------------------------------------------------
__global__ __launch_bounds__(256) void k_prep(
    const float* __restrict__ x,
    const float* __restrict__ Wq, const float* __restrict__ Wk,
    const float* __restrict__ Wv, const float* __restrict__ Wo,
    __bf16* __restrict__ Wt, __bf16* __restrict__ xb)
{
    __shared__ __bf16 t[64][65];
    if (blockIdx.z == 4) {
        size_t base = ((size_t)(blockIdx.y * 16 + blockIdx.x)) * 16384;
        for (int j = 0; j < 8; ++j) {
            size_t i = base + (size_t)j * 2048 + (size_t)threadIdx.x * 8;
            float4 f0 = *(const float4*)&x[i];
            float4 f1 = *(const float4*)&x[i + 4];
            union { uint4 u; __bf16 h[8]; } cv;
            cv.h[0] = (__bf16)f0.x; cv.h[1] = (__bf16)f0.y;
            cv.h[2] = (__bf16)f0.z; cv.h[3] = (__bf16)f0.w;
            cv.h[4] = (__bf16)f1.x; cv.h[5] = (__bf16)f1.y;
            cv.h[6] = (__bf16)f1.z; cv.h[7] = (__bf16)f1.w;
            *(uint4*)&xb[i] = cv.u;
        }
        return;
    }
    const float* src = (blockIdx.z == 0) ? Wq : (blockIdx.z == 1) ? Wk
                      : (blockIdx.z == 2) ? Wv : Wo;
    __bf16* dst = Wt + (size_t)blockIdx.z * (1024u * 1024u);
    int tr = blockIdx.y * 64, tc = blockIdx.x * 64;
    for (int j = 0; j < 4; ++j) {
        int id = threadIdx.x + j * 256;          // 0..1023
        int r = id >> 4;                         // 0..63
        int c4 = (id & 15) * 4;                  // 0,4,..,60
        float4 f = *(const float4*)&src[(size_t)(tr + r) * 1024 + tc + c4];
        t[r][c4 + 0] = (__bf16)f.x; t[r][c4 + 1] = (__bf16)f.y;
        t[r][c4 + 2] = (__bf16)f.z; t[r][c4 + 3] = (__bf16)f.w;
    }
    __syncthreads();
    for (int j = 0; j < 2; ++j) {
        int id = threadIdx.x + j * 256;          // 0..511
        int r = id >> 3;                         // out row 0..63
        int c8 = (id & 7) * 8;                   // col group
        union { uint4 u; __bf16 h[8]; } pk;
        for (int i = 0; i < 8; ++i) pk.h[i] = t[c8 + i][r];
        *(uint4*)&dst[(size_t)(tc + r) * 1024 + tr + c8] = pk.u;
    }
}

// ---------------------------------------------------------------------------
// 128x128 GEMM: Y[4096][1024] = A * W + bias.  (R7: XCD-chunked swizzle)
// ---------------------------------------------------------------------------
template <int MODE, bool WT>
__global__ __launch_bounds__(256) void k_gemm128(
    const void* __restrict__ Ap,
    const void* __restrict__ W0, const void* __restrict__ W1,
    const void* __restrict__ W2,
    const float* __restrict__ b0, const float* __restrict__ b1,
    const float* __restrict__ b2, void* __restrict__ dstp)
{
    constexpr int AST = WT ? 64 : 72;
    alignas(16) __shared__ __bf16 SH[18432];   // 36 KB: staging + C restage
    __bf16* As = SH;
    __bf16* Bs = SH + 128 * AST;

    const int tid = threadIdx.x;
    const int z = blockIdx.z;
    const int lid = blockIdx.x + (blockIdx.y << 3);      // 0..255
    const int mt = ((lid & 7) << 2) + ((lid >> 3) >> 3); // XCD-chunked m
    const int nt = (lid >> 3) & 7;
    const int m0 = mt * 128;
    const int n0 = nt * 128;
    const void* W     = (z == 0) ? W0 : (z == 1) ? W1 : W2;
    const float* bias = (z == 0) ? b0 : (z == 1) ? b1 : b2;

    const int wid = tid >> 6, lane = tid & 63;
    const int quad = lane >> 4, l16 = lane & 15;
    const int wRow = (wid >> 1) * 64, wCol = (wid & 1) * 64;

    f32x4 acc[4][4];
    const f32x4 zero = {0.f, 0.f, 0.f, 0.f};
    for (int mi = 0; mi < 4; ++mi)
        for (int ni = 0; ni < 4; ++ni) acc[mi][ni] = zero;

    const int srow = tid >> 3;
    const int sseg = (tid & 7) * 8;
    const int bkrow = tid >> 4;
    const int bnseg = (tid & 15) * 8;
    const int arow = lane >> 3;
    const int akoff = ((lane & 7) * 8) ^ (arow * 8);
    const int sw = (l16 & 7) * 8;

    for (int k0 = 0; k0 < D_MODEL; k0 += 64) {
        __syncthreads();
        if (WT) {
            const __bf16* Ab = (const __bf16*)Ap;
            const __bf16* Bt = (const __bf16*)W;
            for (int it = 0; it < 4; ++it) {
                int row = wid * 32 + it * 8;
                ASYNC_CP16(&Ab[(size_t)(m0 + row + arow) * D_MODEL + k0 + akoff],
                           &As[row * 64]);
                ASYNC_CP16(&Bt[(size_t)(n0 + row + arow) * D_MODEL + k0 + akoff],
                           &Bs[row * 64]);
            }
        } else {
            if (MODE == 0) {
                const float* A = (const float*)Ap;
                for (int it = 0; it < 4; ++it) {
                    int row = srow + it * 32;
                    const float* src = &A[(size_t)(m0 + row) * D_MODEL + k0 + sseg];
                    float4 f0 = *(const float4*)src;
                    float4 f1 = *(const float4*)(src + 4);
                    union { uint4 u; __bf16 h[8]; } cv;
                    cv.h[0] = (__bf16)f0.x; cv.h[1] = (__bf16)f0.y;
                    cv.h[2] = (__bf16)f0.z; cv.h[3] = (__bf16)f0.w;
                    cv.h[4] = (__bf16)f1.x; cv.h[5] = (__bf16)f1.y;
                    cv.h[6] = (__bf16)f1.z; cv.h[7] = (__bf16)f1.w;
                    *(uint4*)&As[row * AST + sseg] = cv.u;
                }
            } else {
                const __bf16* A = (const __bf16*)Ap;
                for (int it = 0; it < 4; ++it) {
                    int row = srow + it * 32;
                    uint4 va = *(const uint4*)&A[(size_t)(m0 + row) * D_MODEL + k0 + sseg];
                    *(uint4*)&As[row * AST + sseg] = va;
                }
            }
            const float* Wf = (const float*)W;
            for (int it = 0; it < 4; ++it) {
                int krow = bkrow + it * 16;
                const float* src = &Wf[(size_t)(k0 + krow) * D_MODEL + n0 + bnseg];
                float4 f0 = *(const float4*)src;
                float4 f1 = *(const float4*)(src + 4);
                Bs[(bnseg + 0) * AST + krow] = (__bf16)f0.x;
                Bs[(bnseg + 1) * AST + krow] = (__bf16)f0.y;
                Bs[(bnseg + 2) * AST + krow] = (__bf16)f0.z;
                Bs[(bnseg + 3) * AST + krow] = (__bf16)f0.w;
                Bs[(bnseg + 4) * AST + krow] = (__bf16)f1.x;
                Bs[(bnseg + 5) * AST + krow] = (__bf16)f1.y;
                Bs[(bnseg + 6) * AST + krow] = (__bf16)f1.z;
                Bs[(bnseg + 7) * AST + krow] = (__bf16)f1.w;
            }
        }
        __syncthreads();
        for (int kk = 0; kk < 64; kk += 32) {
            bfrag af[4], bf[4];
            if (WT) {
                int ko = (kk + quad * 8) ^ sw;
                for (int mi = 0; mi < 4; ++mi)
                    af[mi] = *(const bfrag*)&As[(wRow + mi * 16 + l16) * 64 + ko];
                for (int ni = 0; ni < 4; ++ni)
                    bf[ni] = *(const bfrag*)&Bs[(wCol + ni * 16 + l16) * 64 + ko];
            } else {
                for (int mi = 0; mi < 4; ++mi)
                    af[mi] = *(const bfrag*)&As[(wRow + mi * 16 + l16) * AST + kk + quad * 8];
                for (int ni = 0; ni < 4; ++ni)
                    bf[ni] = *(const bfrag*)&Bs[(wCol + ni * 16 + l16) * AST + kk + quad * 8];
            }
            for (int mi = 0; mi < 4; ++mi)
                for (int ni = 0; ni < 4; ++ni)
                    acc[mi][ni] = MFMA(af[mi], bf[ni], acc[mi][ni]);
        }
    }

    if (MODE == 0) {
        float biasv[4];
        for (int ni = 0; ni < 4; ++ni) biasv[ni] = bias[n0 + wCol + ni * 16 + l16];
        const int b = m0 >> 11, m0s = m0 & 2047, h0 = n0 >> 6;
        __syncthreads();
        if (z < 2) {
            for (int mi = 0; mi < 4; ++mi)
                for (int ni = 0; ni < 4; ++ni) {
                    int col = wCol + ni * 16 + l16;
                    for (int r = 0; r < 4; ++r) {
                        float v = acc[mi][ni][r] + biasv[ni];
                        if (z == 0) v *= SCALE_LOG2;
                        SH[(wRow + mi * 16 + quad * 4 + r) * 136 + col] = (__bf16)v;
                    }
                }
            __syncthreads();
            __bf16* qk = (__bf16*)dstp + (size_t)z * (MROWS * (size_t)D_MODEL);
            for (int i = 0; i < 8; ++i) {
                int rid = i * 32 + (tid >> 3);
                int hl = rid >> 7, sl = rid & 127;
                int dcol = (tid & 7) * 8;
                uint4 v = *(const uint4*)&SH[sl * 136 + hl * 64 + dcol];
                *(uint4*)&qk[(((size_t)b * NH + h0 + hl) * SEQ + m0s + sl) * HD + dcol] = v;
            }
        } else {
            for (int mi = 0; mi < 4; ++mi)
                for (int ni = 0; ni < 4; ++ni) {
                    int col = wCol + ni * 16 + l16;
                    int s0 = wRow + mi * 16 + quad * 4;
                    union { unsigned long long u; __bf16 h4[4]; } pk;
                    for (int r = 0; r < 4; ++r)
                        pk.h4[r] = (__bf16)(acc[mi][ni][r] + biasv[ni]);
                    *(unsigned long long*)&SH[col * 136 + s0] = pk.u;
                }
            __syncthreads();
            __bf16* vv = (__bf16*)dstp + (size_t)2 * (MROWS * (size_t)D_MODEL);
            for (int i = 0; i < 8; ++i) {
                int rid = i * 16 + (tid >> 4);
                int hl = rid >> 6, d = rid & 63;
                int sc = (tid & 15) * 8;
                uint4 v = *(const uint4*)&SH[rid * 136 + sc];
                *(uint4*)&vv[(((size_t)b * NH + h0 + hl) * HD + d) * SEQ + m0s + sc] = v;
            }
        }
    } else {
        for (int mi = 0; mi < 4; ++mi)
            for (int ni = 0; ni < 4; ++ni) {
                int gn = n0 + wCol + ni * 16 + l16;
                float bv = bias[gn];
                for (int r = 0; r < 4; ++r) {
                    int gm = m0 + wRow + mi * 16 + quad * 4 + r;
                    ((float*)dstp)[(size_t)gm * D_MODEL + gn] = acc[mi][ni][r] + bv;
                }
            }
    }
}

// ---------------------------------------------------------------------------
// Output GEMM (round-0 proven): Y[4096][1024] fp32 = A(bf16)*WoT(bf16)+bo.
// 64(M)x128(N) tiles -> grid (8,64), 512 blocks (2/CU). (R7: XCD swizzle)
// ---------------------------------------------------------------------------
__global__ __launch_bounds__(256) void k_gemm_out(
    const __bf16* __restrict__ A, const __bf16* __restrict__ Bt,
    const float* __restrict__ bias, float* __restrict__ dst)
{
    alignas(16) __shared__ __bf16 As[64 * 64];    // 8 KB
    alignas(16) __shared__ __bf16 Bs[128 * 64];   // 16 KB

    const int tid = threadIdx.x;
    const int lid = blockIdx.x + (blockIdx.y << 3);      // 0..511
    const int mt = ((lid & 7) << 3) + ((lid >> 3) >> 3); // XCD-chunked m
    const int nt = (lid >> 3) & 7;
    const int m0 = mt * 64;
    const int n0 = nt * 128;
    const int wid = tid >> 6, lane = tid & 63;
    const int quad = lane >> 4, l16 = lane & 15;
    const int wRow = (wid >> 1) * 32, wCol = (wid & 1) * 64;

    f32x4 acc[2][4];
    const f32x4 zero = {0.f, 0.f, 0.f, 0.f};
    for (int mi = 0; mi < 2; ++mi)
        for (int ni = 0; ni < 4; ++ni) acc[mi][ni] = zero;

    const int arow = lane >> 3;
    const int akoff = ((lane & 7) * 8) ^ (arow * 8);
    const int sw = (l16 & 7) * 8;

    for (int k0 = 0; k0 < D_MODEL; k0 += 64) {
        __syncthreads();
        for (int it = 0; it < 2; ++it) {
            int row = wid * 16 + it * 8;
            ASYNC_CP16(&A[(size_t)(m0 + row + arow) * D_MODEL + k0 + akoff],
                       &As[row * 64]);
        }
        for (int it = 0; it < 4; ++it) {
            int row = wid * 32 + it * 8;
            ASYNC_CP16(&Bt[(size_t)(n0 + row + arow) * D_MODEL + k0 + akoff],
                       &Bs[row * 64]);
        }
        __syncthreads();
        for (int kk = 0; kk < 64; kk += 32) {
            int ko = (kk + quad * 8) ^ sw;
            bfrag af[2], bf[4];
            for (int mi = 0; mi < 2; ++mi)
                af[mi] = *(const bfrag*)&As[(wRow + mi * 16 + l16) * 64 + ko];
            for (int ni = 0; ni < 4; ++ni)
                bf[ni] = *(const bfrag*)&Bs[(wCol + ni * 16 + l16) * 64 + ko];
            for (int mi = 0; mi < 2; ++mi)
                for (int ni = 0; ni < 4; ++ni)
                    acc[mi][ni] = MFMA(af[mi], bf[ni], acc[mi][ni]);
        }
    }

    for (int mi = 0; mi < 2; ++mi)
        for (int ni = 0; ni < 4; ++ni) {
            int gn = n0 + wCol + ni * 16 + l16;
            float bv = bias[gn];
            for (int r = 0; r < 4; ++r) {
                int gm = m0 + wRow + mi * 16 + quad * 4 + r;
                dst[(size_t)gm * D_MODEL + gn] = acc[mi][ni][r] + bv;
            }
        }
}

// ---------------------------------------------------------------------------
// Flash attention (causal), S^T formulation, v13: v11 (merged balanced pairs,
// measured 47.0 us) + T5 setprio around MFMA clusters. v11's regime is
// exactly m191's (+4-7% attn): independent blocks at different phases
// (per-block ntA varies with u; 2 blocks/CU progress independently).
// setprio is a pure scheduler hint: no correctness/register impact.
// v12's fusion REVERTED (measured -23%: VGPR 88->116 scheduling loss).
// ---------------------------------------------------------------------------
__global__ __launch_bounds__(256) void k_attn(
    const __bf16* __restrict__ Q, const __bf16* __restrict__ K,
    const __bf16* __restrict__ Vt, __bf16* __restrict__ O)
{
    alignas(16) __shared__ __bf16 Ks[64 * 64];     // 8 KB, swizzled
    alignas(16) __shared__ __bf16 Vts[64 * 64];    // 8 KB, swizzled [d][key]
    alignas(16) __shared__ __bf16 Ps[4][16 * 64];  // 8 KB, swizzled [qrow][key]

    const int tid = threadIdx.x, wid = tid >> 6, lane = tid & 63;
    const int quad = lane >> 4, l16 = lane & 15;
    const int u = (blockIdx.x + blockIdx.y + blockIdx.z) & 15;  // 0..15
    const int h = blockIdx.y, b = blockIdx.z;
    const int qbA = 31 - u, qbB = u;               // pair: long + short
    const size_t bh = ((size_t)b * NH + h) * SEQ * HD;
    const __bf16* Kg  = K + bh;
    const __bf16* Vtg = Vt + ((size_t)b * NH + h) * HD * SEQ;  // [d][s]

    const __bf16* QgA = Q + bh + (size_t)qbA * 64 * HD;
    const __bf16* QgB = Q + bh + (size_t)qbB * 64 * HD;
    bfrag qfA0 = *(const bfrag*)&QgA[(size_t)(wid * 16 + l16) * HD + quad * 8];
    bfrag qfA1 = *(const bfrag*)&QgA[(size_t)(wid * 16 + l16) * HD + 32 + quad * 8];
    bfrag qfB0 = *(const bfrag*)&QgB[(size_t)(wid * 16 + l16) * HD + quad * 8];
    bfrag qfB1 = *(const bfrag*)&QgB[(size_t)(wid * 16 + l16) * HD + 32 + quad * 8];

    // constant all-ones B-fragment for the denominator MFMA
    union { uint4 u; bfrag f; } onesu;
    onesu.u = make_uint4(0x3F803F80u, 0x3F803F80u, 0x3F803F80u, 0x3F803F80u);
    const bfrag onesf = onesu.f;

    const f32x4 zero = {0.f, 0.f, 0.f, 0.f};
    f32x4 oA[4], oB[4];
    for (int dt = 0; dt < 4; ++dt) { oA[dt] = zero; oB[dt] = zero; }
    f32x4 o_lA = zero, o_lB = zero;                // row-sum accumulators
    const int qA = qbA * 64 + wid * 16 + l16;
    const int qB = qbB * 64 + wid * 16 + l16;
    const int ntA = qbA + 1, ntB = qbB + 1;        // ntB <= 16 < ntA
    const int sw = (l16 & 7) * 8;

    const int row0 = tid >> 3, seg = (tid & 7) * 8;
    const int sseg = seg ^ ((row0 & 7) * 8);       // swizzled dest k-offset

    const __bf16* Kr0 = &Kg[(size_t)row0 * HD + seg];
    const __bf16* Kr1 = &Kg[(size_t)(row0 + 32) * HD + seg];
    const __bf16* Vr0 = &Vtg[(size_t)row0 * SEQ + seg];
    const __bf16* Vr1 = &Vtg[(size_t)(row0 + 32) * SEQ + seg];

    uint4 kreg0 = *(const uint4*)(Kr0);
    uint4 kreg1 = *(const uint4*)(Kr1);
    uint4 vreg0 = *(const uint4*)(Vr0);
    uint4 vreg1 = *(const uint4*)(Vr1);

    for (int t = 0; t < ntA; ++t) {
        const int j0 = t * 64;
        __syncthreads();
        *(uint4*)&Ks[row0 * 64 + sseg] = kreg0;
        *(uint4*)&Ks[(row0 + 32) * 64 + sseg] = kreg1;
        *(uint4*)&Vts[row0 * 64 + sseg] = vreg0;
        *(uint4*)&Vts[(row0 + 32) * 64 + sseg] = vreg1;
        if (t + 1 < ntA) {
            const size_t j1k = (size_t)(j0 + 64) * HD;
            const int j1v = j0 + 64;
            kreg0 = *(const uint4*)(Kr0 + j1k);
            kreg1 = *(const uint4*)(Kr1 + j1k);
            vreg0 = *(const uint4*)(Vr0 + j1v);
            vreg1 = *(const uint4*)(Vr1 + j1v);
        }
        __syncthreads();

        // ---- pass A (always) ----
        {
            f32x4 st[4];
            __builtin_amdgcn_s_setprio(1);
            for (int kt = 0; kt < 4; ++kt) {
                bfrag ka0 = *(const bfrag*)&Ks[(kt * 16 + l16) * 64 + ((quad * 8) ^ sw)];
                bfrag ka1 = *(const bfrag*)&Ks[(kt * 16 + l16) * 64 + ((32 + quad * 8) ^ sw)];
                st[kt] = MFMA(ka1, qfA1, MFMA(ka0, qfA0, zero));
            }
            __builtin_amdgcn_s_setprio(0);

            if (t == ntA - 1) {
                for (int kt = 0; kt < 4; ++kt)
                    for (int r = 0; r < 4; ++r) {
                        float v = (j0 + kt * 16 + quad * 4 + r > qA) ? NEG_BIG : st[kt][r];
                        st[kt][r] = exp2f(v);
                    }
            } else {
                for (int kt = 0; kt < 4; ++kt)
                    for (int r = 0; r < 4; ++r)
                        st[kt][r] = exp2f(st[kt][r]);
            }

            for (int kt = 0; kt < 4; ++kt) {
                union { unsigned long long u; __bf16 h4[4]; } pk;
                for (int r = 0; r < 4; ++r) pk.h4[r] = (__bf16)st[kt][r];
                *(unsigned long long*)&Ps[wid][l16 * 64 + ((kt * 16 + quad * 4) ^ sw)] = pk.u;
            }
            asm volatile("s_waitcnt lgkmcnt(0)" ::: "memory");

            __builtin_amdgcn_s_setprio(1);
            for (int c = 0; c < 2; ++c) {
                int ko = (c * 32 + quad * 8) ^ sw;
                bfrag pf = *(const bfrag*)&Ps[wid][l16 * 64 + ko];
                for (int dt = 0; dt < 4; ++dt) {
                    bfrag vf = *(const bfrag*)&Vts[(dt * 16 + l16) * 64 + ko];
                    oA[dt] = MFMA(pf, vf, oA[dt]);
                }
                o_lA = MFMA(pf, onesf, o_lA);
            }
            __builtin_amdgcn_s_setprio(0);
        }

        // ---- pass B (first ntB tiles only) ----
        if (t < ntB) {
            f32x4 st[4];
            __builtin_amdgcn_s_setprio(1);
            for (int kt = 0; kt < 4; ++kt) {
                bfrag ka0 = *(const bfrag*)&Ks[(kt * 16 + l16) * 64 + ((quad * 8) ^ sw)];
                bfrag ka1 = *(const bfrag*)&Ks[(kt * 16 + l16) * 64 + ((32 + quad * 8) ^ sw)];
                st[kt] = MFMA(ka1, qfB1, MFMA(ka0, qfB0, zero));
            }
            __builtin_amdgcn_s_setprio(0);

            if (t == ntB - 1) {
                for (int kt = 0; kt < 4; ++kt)
                    for (int r = 0; r < 4; ++r) {
                        float v = (j0 + kt * 16 + quad * 4 + r > qB) ? NEG_BIG : st[kt][r];
                        st[kt][r] = exp2f(v);
                    }
            } else {
                for (int kt = 0; kt < 4; ++kt)
                    for (int r = 0; r < 4; ++r)
                        st[kt][r] = exp2f(st[kt][r]);
            }

            // Ps reuse after pass A's reads: same-wave ds ordering via
            // the write below then lgkmcnt(0) before the reads.
            for (int kt = 0; kt < 4; ++kt) {
                union { unsigned long long u; __bf16 h4[4]; } pk;
                for (int r = 0; r < 4; ++r) pk.h4[r] = (__bf16)st[kt][r];
                *(unsigned long long*)&Ps[wid][l16 * 64 + ((kt * 16 + quad * 4) ^ sw)] = pk.u;
            }
            asm volatile("s_waitcnt lgkmcnt(0)" ::: "memory");

            __builtin_amdgcn_s_setprio(1);
            for (int c = 0; c < 2; ++c) {
                int ko = (c * 32 + quad * 8) ^ sw;
                bfrag pf = *(const bfrag*)&Ps[wid][l16 * 64 + ko];
                for (int dt = 0; dt < 4; ++dt) {
                    bfrag vf = *(const bfrag*)&Vts[(dt * 16 + l16) * 64 + ko];
                    oB[dt] = MFMA(pf, vf, oB[dt]);
                }
                o_lB = MFMA(pf, onesf, o_lB);
            }
            __builtin_amdgcn_s_setprio(0);
        }
    }

    // epilogues: normalize by row-sums, write O for both q-blocks
    for (int r = 0; r < 4; ++r) {
        float inv = 1.0f / o_lA[r];
        size_t base = ((size_t)b * SEQ + qbA * 64 + wid * 16 + quad * 4 + r) * D_MODEL
                    + (size_t)h * HD;
        for (int dt = 0; dt < 4; ++dt)
            O[base + dt * 16 + l16] = (__bf16)(oA[dt][r] * inv);
    }
    for (int r = 0; r < 4; ++r) {
        float inv = 1.0f / o_lB[r];
        size_t base = ((size_t)b * SEQ + qbB * 64 + wid * 16 + quad * 4 + r) * D_MODEL
                    + (size_t)h * HD;
        for (int dt = 0; dt < 4; ++dt)
            O[base + dt * 16 + l16] = (__bf16)(oB[dt][r] * inv);
    }
}

// ---------------------------------------------------------------------------
extern "C" void kernel_launch(void* const* d_in, const int* in_sizes, int n_in,
                              void* d_out, int out_size, void* d_ws, size_t ws_size,
                              hipStream_t stream)
{
    const float* x  = (const float*)d_in[0];
    const float* Wq = (const float*)d_in[1];
    const float* bq = (const float*)d_in[2];
    const float* Wk = (const float*)d_in[3];
    const float* bk = (const float*)d_in[4];
    const float* Wv = (const float*)d_in[5];
    const float* bv = (const float*)d_in[6];
    const float* Wo = (const float*)d_in[7];
    const float* bo = (const float*)d_in[8];

    __bf16* ws = (__bf16*)d_ws;
    const size_t M1 = 1024u * 1024u;
    __bf16* qkv    = ws;                      // Q @0, K @4M, Vt @8M (24 MB)
    __bf16* attn_o = ws + 12 * M1;            // 4M (8 MB)
    __bf16* Wt     = ws + 16 * M1;            // 4M (8 MB)
    __bf16* xb     = ws + 20 * M1;            // 4M (8 MB) -> 48 MB total

    const bool fast = ws_size >= (size_t)48 * 1024 * 1024;

    if (fast) {
        k_prep<<<dim3(16, 16, 5), 256, 0, stream>>>(x, Wq, Wk, Wv, Wo, Wt, xb);
        k_gemm128<0, true><<<dim3(8, 32, 3), 256, 0, stream>>>(
            xb, Wt, Wt + M1, Wt + 2 * M1, bq, bk, bv, qkv);
        k_attn<<<dim3(16, 16, 2), 256, 0, stream>>>(
            qkv, qkv + 4 * M1, qkv + 8 * M1, attn_o);
        k_gemm_out<<<dim3(8, 64), 256, 0, stream>>>(
            attn_o, Wt + 3 * M1, bo, (float*)d_out);
    } else {
        k_gemm128<0, false><<<dim3(8, 32, 3), 256, 0, stream>>>(
            x, Wq, Wk, Wv, bq, bk, bv, qkv);
        k_attn<<<dim3(16, 16, 2), 256, 0, stream>>>(
            qkv, qkv + 4 * M1, qkv + 8 * M1, attn_o);
        k_gemm128<1, false><<<dim3(8, 32, 1), 256, 0, stream>>>(
            attn_o, Wo, Wo, Wo, bo, bo, bo, (float*)d_out);
    }
}

// Round 14
// 183.033 us; speedup vs baseline: 1.0512x; 1.0252x over previous
//
#include <hip/hip_runtime.h>

typedef __attribute__((ext_vector_type(8))) __bf16 bfrag;
typedef __attribute__((ext_vector_type(4))) float f32x4;

#define MFMA(a, b, c) __builtin_amdgcn_mfma_f32_16x16x32_bf16((a), (b), (c), 0, 0, 0)

#define D_MODEL 1024
#define SEQ     2048
#define NB      2
#define NH      16
#define HD      64
#define MROWS   (NB * SEQ)   // 4096

#define SCALE_LOG2 0.18033688011112043f   // log2(e)/sqrt(HD), folded into Q
#define NEG_BIG    (-3.0e38f)

#define GLOBAL_AS(p) ((const __attribute__((address_space(1))) void*)(p))
#define LDS_AS(p)    ((__attribute__((address_space(3))) void*)(p))
#define ASYNC_CP16(g, l) __builtin_amdgcn_global_load_lds(GLOBAL_AS(g), LDS_AS(l), 16, 0, 0)

// ---------------------------------------------------------------------------
// Prep: z<4 -> transpose weight z fp32 [K][N] -> bf16 [N][K]; z==4 -> x cvt.
// (R7: float4 transpose loads)
// ---------------------------------------------------------------------------
__global__ __launch_bounds__(256) void k_prep(
    const float* __restrict__ x,
    const float* __restrict__ Wq, const float* __restrict__ Wk,
    const float* __restrict__ Wv, const float* __restrict__ Wo,
    __bf16* __restrict__ Wt, __bf16* __restrict__ xb)
{
    __shared__ __bf16 t[64][65];
    if (blockIdx.z == 4) {
        size_t base = ((size_t)(blockIdx.y * 16 + blockIdx.x)) * 16384;
        for (int j = 0; j < 8; ++j) {
            size_t i = base + (size_t)j * 2048 + (size_t)threadIdx.x * 8;
            float4 f0 = *(const float4*)&x[i];
            float4 f1 = *(const float4*)&x[i + 4];
            union { uint4 u; __bf16 h[8]; } cv;
            cv.h[0] = (__bf16)f0.x; cv.h[1] = (__bf16)f0.y;
            cv.h[2] = (__bf16)f0.z; cv.h[3] = (__bf16)f0.w;
            cv.h[4] = (__bf16)f1.x; cv.h[5] = (__bf16)f1.y;
            cv.h[6] = (__bf16)f1.z; cv.h[7] = (__bf16)f1.w;
            *(uint4*)&xb[i] = cv.u;
        }
        return;
    }
    const float* src = (blockIdx.z == 0) ? Wq : (blockIdx.z == 1) ? Wk
                      : (blockIdx.z == 2) ? Wv : Wo;
    __bf16* dst = Wt + (size_t)blockIdx.z * (1024u * 1024u);
    int tr = blockIdx.y * 64, tc = blockIdx.x * 64;
    for (int j = 0; j < 4; ++j) {
        int id = threadIdx.x + j * 256;          // 0..1023
        int r = id >> 4;                         // 0..63
        int c4 = (id & 15) * 4;                  // 0,4,..,60
        float4 f = *(const float4*)&src[(size_t)(tr + r) * 1024 + tc + c4];
        t[r][c4 + 0] = (__bf16)f.x; t[r][c4 + 1] = (__bf16)f.y;
        t[r][c4 + 2] = (__bf16)f.z; t[r][c4 + 3] = (__bf16)f.w;
    }
    __syncthreads();
    for (int j = 0; j < 2; ++j) {
        int id = threadIdx.x + j * 256;          // 0..511
        int r = id >> 3;                         // out row 0..63
        int c8 = (id & 7) * 8;                   // col group
        union { uint4 u; __bf16 h[8]; } pk;
        for (int i = 0; i < 8; ++i) pk.h[i] = t[c8 + i][r];
        *(uint4*)&dst[(size_t)(tc + r) * 1024 + tr + c8] = pk.u;
    }
}

// ---------------------------------------------------------------------------
// 128x128 GEMM: Y[4096][1024] = A * W + bias.  (R7: XCD-chunked swizzle)
// ---------------------------------------------------------------------------
template <int MODE, bool WT>
__global__ __launch_bounds__(256) void k_gemm128(
    const void* __restrict__ Ap,
    const void* __restrict__ W0, const void* __restrict__ W1,
    const void* __restrict__ W2,
    const float* __restrict__ b0, const float* __restrict__ b1,
    const float* __restrict__ b2, void* __restrict__ dstp)
{
    constexpr int AST = WT ? 64 : 72;
    alignas(16) __shared__ __bf16 SH[18432];   // 36 KB: staging + C restage
    __bf16* As = SH;
    __bf16* Bs = SH + 128 * AST;

    const int tid = threadIdx.x;
    const int z = blockIdx.z;
    const int lid = blockIdx.x + (blockIdx.y << 3);      // 0..255
    const int mt = ((lid & 7) << 2) + ((lid >> 3) >> 3); // XCD-chunked m
    const int nt = (lid >> 3) & 7;
    const int m0 = mt * 128;
    const int n0 = nt * 128;
    const void* W     = (z == 0) ? W0 : (z == 1) ? W1 : W2;
    const float* bias = (z == 0) ? b0 : (z == 1) ? b1 : b2;

    const int wid = tid >> 6, lane = tid & 63;
    const int quad = lane >> 4, l16 = lane & 15;
    const int wRow = (wid >> 1) * 64, wCol = (wid & 1) * 64;

    f32x4 acc[4][4];
    const f32x4 zero = {0.f, 0.f, 0.f, 0.f};
    for (int mi = 0; mi < 4; ++mi)
        for (int ni = 0; ni < 4; ++ni) acc[mi][ni] = zero;

    const int srow = tid >> 3;
    const int sseg = (tid & 7) * 8;
    const int bkrow = tid >> 4;
    const int bnseg = (tid & 15) * 8;
    const int arow = lane >> 3;
    const int akoff = ((lane & 7) * 8) ^ (arow * 8);
    const int sw = (l16 & 7) * 8;

    for (int k0 = 0; k0 < D_MODEL; k0 += 64) {
        __syncthreads();
        if (WT) {
            const __bf16* Ab = (const __bf16*)Ap;
            const __bf16* Bt = (const __bf16*)W;
            for (int it = 0; it < 4; ++it) {
                int row = wid * 32 + it * 8;
                ASYNC_CP16(&Ab[(size_t)(m0 + row + arow) * D_MODEL + k0 + akoff],
                           &As[row * 64]);
                ASYNC_CP16(&Bt[(size_t)(n0 + row + arow) * D_MODEL + k0 + akoff],
                           &Bs[row * 64]);
            }
        } else {
            if (MODE == 0) {
                const float* A = (const float*)Ap;
                for (int it = 0; it < 4; ++it) {
                    int row = srow + it * 32;
                    const float* src = &A[(size_t)(m0 + row) * D_MODEL + k0 + sseg];
                    float4 f0 = *(const float4*)src;
                    float4 f1 = *(const float4*)(src + 4);
                    union { uint4 u; __bf16 h[8]; } cv;
                    cv.h[0] = (__bf16)f0.x; cv.h[1] = (__bf16)f0.y;
                    cv.h[2] = (__bf16)f0.z; cv.h[3] = (__bf16)f0.w;
                    cv.h[4] = (__bf16)f1.x; cv.h[5] = (__bf16)f1.y;
                    cv.h[6] = (__bf16)f1.z; cv.h[7] = (__bf16)f1.w;
                    *(uint4*)&As[row * AST + sseg] = cv.u;
                }
            } else {
                const __bf16* A = (const __bf16*)Ap;
                for (int it = 0; it < 4; ++it) {
                    int row = srow + it * 32;
                    uint4 va = *(const uint4*)&A[(size_t)(m0 + row) * D_MODEL + k0 + sseg];
                    *(uint4*)&As[row * AST + sseg] = va;
                }
            }
            const float* Wf = (const float*)W;
            for (int it = 0; it < 4; ++it) {
                int krow = bkrow + it * 16;
                const float* src = &Wf[(size_t)(k0 + krow) * D_MODEL + n0 + bnseg];
                float4 f0 = *(const float4*)src;
                float4 f1 = *(const float4*)(src + 4);
                Bs[(bnseg + 0) * AST + krow] = (__bf16)f0.x;
                Bs[(bnseg + 1) * AST + krow] = (__bf16)f0.y;
                Bs[(bnseg + 2) * AST + krow] = (__bf16)f0.z;
                Bs[(bnseg + 3) * AST + krow] = (__bf16)f0.w;
                Bs[(bnseg + 4) * AST + krow] = (__bf16)f1.x;
                Bs[(bnseg + 5) * AST + krow] = (__bf16)f1.y;
                Bs[(bnseg + 6) * AST + krow] = (__bf16)f1.z;
                Bs[(bnseg + 7) * AST + krow] = (__bf16)f1.w;
            }
        }
        __syncthreads();
        for (int kk = 0; kk < 64; kk += 32) {
            bfrag af[4], bf[4];
            if (WT) {
                int ko = (kk + quad * 8) ^ sw;
                for (int mi = 0; mi < 4; ++mi)
                    af[mi] = *(const bfrag*)&As[(wRow + mi * 16 + l16) * 64 + ko];
                for (int ni = 0; ni < 4; ++ni)
                    bf[ni] = *(const bfrag*)&Bs[(wCol + ni * 16 + l16) * 64 + ko];
            } else {
                for (int mi = 0; mi < 4; ++mi)
                    af[mi] = *(const bfrag*)&As[(wRow + mi * 16 + l16) * AST + kk + quad * 8];
                for (int ni = 0; ni < 4; ++ni)
                    bf[ni] = *(const bfrag*)&Bs[(wCol + ni * 16 + l16) * AST + kk + quad * 8];
            }
            for (int mi = 0; mi < 4; ++mi)
                for (int ni = 0; ni < 4; ++ni)
                    acc[mi][ni] = MFMA(af[mi], bf[ni], acc[mi][ni]);
        }
    }

    if (MODE == 0) {
        float biasv[4];
        for (int ni = 0; ni < 4; ++ni) biasv[ni] = bias[n0 + wCol + ni * 16 + l16];
        const int b = m0 >> 11, m0s = m0 & 2047, h0 = n0 >> 6;
        __syncthreads();
        if (z < 2) {
            for (int mi = 0; mi < 4; ++mi)
                for (int ni = 0; ni < 4; ++ni) {
                    int col = wCol + ni * 16 + l16;
                    for (int r = 0; r < 4; ++r) {
                        float v = acc[mi][ni][r] + biasv[ni];
                        if (z == 0) v *= SCALE_LOG2;
                        SH[(wRow + mi * 16 + quad * 4 + r) * 136 + col] = (__bf16)v;
                    }
                }
            __syncthreads();
            __bf16* qk = (__bf16*)dstp + (size_t)z * (MROWS * (size_t)D_MODEL);
            for (int i = 0; i < 8; ++i) {
                int rid = i * 32 + (tid >> 3);
                int hl = rid >> 7, sl = rid & 127;
                int dcol = (tid & 7) * 8;
                uint4 v = *(const uint4*)&SH[sl * 136 + hl * 64 + dcol];
                *(uint4*)&qk[(((size_t)b * NH + h0 + hl) * SEQ + m0s + sl) * HD + dcol] = v;
            }
        } else {
            for (int mi = 0; mi < 4; ++mi)
                for (int ni = 0; ni < 4; ++ni) {
                    int col = wCol + ni * 16 + l16;
                    int s0 = wRow + mi * 16 + quad * 4;
                    union { unsigned long long u; __bf16 h4[4]; } pk;
                    for (int r = 0; r < 4; ++r)
                        pk.h4[r] = (__bf16)(acc[mi][ni][r] + biasv[ni]);
                    *(unsigned long long*)&SH[col * 136 + s0] = pk.u;
                }
            __syncthreads();
            __bf16* vv = (__bf16*)dstp + (size_t)2 * (MROWS * (size_t)D_MODEL);
            for (int i = 0; i < 8; ++i) {
                int rid = i * 16 + (tid >> 4);
                int hl = rid >> 6, d = rid & 63;
                int sc = (tid & 15) * 8;
                uint4 v = *(const uint4*)&SH[rid * 136 + sc];
                *(uint4*)&vv[(((size_t)b * NH + h0 + hl) * HD + d) * SEQ + m0s + sc] = v;
            }
        }
    } else {
        for (int mi = 0; mi < 4; ++mi)
            for (int ni = 0; ni < 4; ++ni) {
                int gn = n0 + wCol + ni * 16 + l16;
                float bv = bias[gn];
                for (int r = 0; r < 4; ++r) {
                    int gm = m0 + wRow + mi * 16 + quad * 4 + r;
                    ((float*)dstp)[(size_t)gm * D_MODEL + gn] = acc[mi][ni][r] + bv;
                }
            }
    }
}

// ---------------------------------------------------------------------------
// Output GEMM (round-0 proven): Y[4096][1024] fp32 = A(bf16)*WoT(bf16)+bo.
// 64(M)x128(N) tiles -> grid (8,64), 512 blocks (2/CU). (R7: XCD swizzle)
// ---------------------------------------------------------------------------
__global__ __launch_bounds__(256) void k_gemm_out(
    const __bf16* __restrict__ A, const __bf16* __restrict__ Bt,
    const float* __restrict__ bias, float* __restrict__ dst)
{
    alignas(16) __shared__ __bf16 As[64 * 64];    // 8 KB
    alignas(16) __shared__ __bf16 Bs[128 * 64];   // 16 KB

    const int tid = threadIdx.x;
    const int lid = blockIdx.x + (blockIdx.y << 3);      // 0..511
    const int mt = ((lid & 7) << 3) + ((lid >> 3) >> 3); // XCD-chunked m
    const int nt = (lid >> 3) & 7;
    const int m0 = mt * 64;
    const int n0 = nt * 128;
    const int wid = tid >> 6, lane = tid & 63;
    const int quad = lane >> 4, l16 = lane & 15;
    const int wRow = (wid >> 1) * 32, wCol = (wid & 1) * 64;

    f32x4 acc[2][4];
    const f32x4 zero = {0.f, 0.f, 0.f, 0.f};
    for (int mi = 0; mi < 2; ++mi)
        for (int ni = 0; ni < 4; ++ni) acc[mi][ni] = zero;

    const int arow = lane >> 3;
    const int akoff = ((lane & 7) * 8) ^ (arow * 8);
    const int sw = (l16 & 7) * 8;

    for (int k0 = 0; k0 < D_MODEL; k0 += 64) {
        __syncthreads();
        for (int it = 0; it < 2; ++it) {
            int row = wid * 16 + it * 8;
            ASYNC_CP16(&A[(size_t)(m0 + row + arow) * D_MODEL + k0 + akoff],
                       &As[row * 64]);
        }
        for (int it = 0; it < 4; ++it) {
            int row = wid * 32 + it * 8;
            ASYNC_CP16(&Bt[(size_t)(n0 + row + arow) * D_MODEL + k0 + akoff],
                       &Bs[row * 64]);
        }
        __syncthreads();
        for (int kk = 0; kk < 64; kk += 32) {
            int ko = (kk + quad * 8) ^ sw;
            bfrag af[2], bf[4];
            for (int mi = 0; mi < 2; ++mi)
                af[mi] = *(const bfrag*)&As[(wRow + mi * 16 + l16) * 64 + ko];
            for (int ni = 0; ni < 4; ++ni)
                bf[ni] = *(const bfrag*)&Bs[(wCol + ni * 16 + l16) * 64 + ko];
            for (int mi = 0; mi < 2; ++mi)
                for (int ni = 0; ni < 4; ++ni)
                    acc[mi][ni] = MFMA(af[mi], bf[ni], acc[mi][ni]);
        }
    }

    for (int mi = 0; mi < 2; ++mi)
        for (int ni = 0; ni < 4; ++ni) {
            int gn = n0 + wCol + ni * 16 + l16;
            float bv = bias[gn];
            for (int r = 0; r < 4; ++r) {
                int gm = m0 + wRow + mi * 16 + quad * 4 + r;
                dst[(size_t)gm * D_MODEL + gn] = acc[mi][ni][r] + bv;
            }
        }
}

// ---------------------------------------------------------------------------
// Flash attention (causal), S^T formulation, v14: WAVE-SPLIT BALANCED PAIRS.
//   512-thread blocks, 8 waves. Waves 0-3 (group A) compute qbA = 31-u;
//   waves 4-7 (group B) compute qbB = u — CONCURRENTLY, sharing the K/V
//   staging (512 threads cover the 64x64 tile with ONE uint4 K + ONE V
//   each). Same total work and grid (16,16,2) = 512 blocks as v13, but
//   16 waves/CU (4/SIMD) instead of 8 -> TRANS/VALU/MFMA from different
//   waves co-schedule (m114). Per-wave state halves (~70 VGPR). B-waves
//   idle at barriers for t >= ntB (wave-uniform guard); their issue slots
//   go to the co-resident block. Inner body = proven R7 code + setprio +
//   ones-trick. LDS 32.8 KB (Ks 8 + Vts 8 + Ps[8] 16).
// ---------------------------------------------------------------------------
__global__ __launch_bounds__(512) void k_attn(
    const __bf16* __restrict__ Q, const __bf16* __restrict__ K,
    const __bf16* __restrict__ Vt, __bf16* __restrict__ O)
{
    alignas(16) __shared__ __bf16 Ks[64 * 64];     // 8 KB, swizzled
    alignas(16) __shared__ __bf16 Vts[64 * 64];    // 8 KB, swizzled [d][key]
    alignas(16) __shared__ __bf16 Ps[8][16 * 64];  // 16 KB, per-wave P^T

    const int tid = threadIdx.x;
    const int wid8 = tid >> 6;                     // 0..7
    const int grp = wid8 >> 2;                     // 0 = A (long), 1 = B
    const int wid = wid8 & 3;                      // wave within group
    const int lane = tid & 63;
    const int quad = lane >> 4, l16 = lane & 15;
    const int u = (blockIdx.x + blockIdx.y + blockIdx.z) & 15;  // 0..15
    const int h = blockIdx.y, b = blockIdx.z;
    const int qb = grp ? u : (31 - u);             // this group's q-block
    const int ntA = 32 - u;                        // loop bound (longest)
    const int nt  = qb + 1;                        // this wave's compute bound
    const size_t bh = ((size_t)b * NH + h) * SEQ * HD;
    const __bf16* Kg  = K + bh;
    const __bf16* Vtg = Vt + ((size_t)b * NH + h) * HD * SEQ;  // [d][s]

    const __bf16* Qg = Q + bh + (size_t)qb * 64 * HD;
    bfrag qf0 = *(const bfrag*)&Qg[(size_t)(wid * 16 + l16) * HD + quad * 8];
    bfrag qf1 = *(const bfrag*)&Qg[(size_t)(wid * 16 + l16) * HD + 32 + quad * 8];

    // constant all-ones B-fragment for the denominator MFMA
    union { uint4 u; bfrag f; } onesu;
    onesu.u = make_uint4(0x3F803F80u, 0x3F803F80u, 0x3F803F80u, 0x3F803F80u);
    const bfrag onesf = onesu.f;

    const f32x4 zero = {0.f, 0.f, 0.f, 0.f};
    f32x4 o[4];
    for (int dt = 0; dt < 4; ++dt) o[dt] = zero;
    f32x4 o_l = zero;                              // row-sum accumulator
    const int q = qb * 64 + wid * 16 + l16;
    const int sw = (l16 & 7) * 8;

    // staging: 512 threads cover the 64x64 tile, 1 uint4 K + 1 uint4 V each
    const int row0 = tid >> 3;                     // 0..63
    const int seg = (tid & 7) * 8;
    const int sseg = seg ^ ((row0 & 7) * 8);       // swizzled dest k-offset

    const __bf16* Kr = &Kg[(size_t)row0 * HD + seg];
    const __bf16* Vr = &Vtg[(size_t)row0 * SEQ + seg];
    uint4 kreg = *(const uint4*)(Kr);
    uint4 vreg = *(const uint4*)(Vr);

    for (int t = 0; t < ntA; ++t) {
        const int j0 = t * 64;
        __syncthreads();
        *(uint4*)&Ks[row0 * 64 + sseg] = kreg;
        *(uint4*)&Vts[row0 * 64 + sseg] = vreg;
        if (t + 1 < ntA) {
            kreg = *(const uint4*)(Kr + (size_t)(j0 + 64) * HD);
            vreg = *(const uint4*)(Vr + j0 + 64);
        }
        __syncthreads();

        if (t < nt) {                              // wave-uniform guard
            f32x4 st[4];
            __builtin_amdgcn_s_setprio(1);
            for (int kt = 0; kt < 4; ++kt) {
                bfrag ka0 = *(const bfrag*)&Ks[(kt * 16 + l16) * 64 + ((quad * 8) ^ sw)];
                bfrag ka1 = *(const bfrag*)&Ks[(kt * 16 + l16) * 64 + ((32 + quad * 8) ^ sw)];
                st[kt] = MFMA(ka1, qf1, MFMA(ka0, qf0, zero));
            }
            __builtin_amdgcn_s_setprio(0);

            // unstabilized softmax: p = exp2(s); masked keys -> exp2(-big)=0
            if (t == nt - 1) {
                for (int kt = 0; kt < 4; ++kt)
                    for (int r = 0; r < 4; ++r) {
                        float v = (j0 + kt * 16 + quad * 4 + r > q) ? NEG_BIG : st[kt][r];
                        st[kt][r] = exp2f(v);
                    }
            } else {
                for (int kt = 0; kt < 4; ++kt)
                    for (int r = 0; r < 4; ++r)
                        st[kt][r] = exp2f(st[kt][r]);
            }

            // P^T writes (swizzled, wave-private)
            for (int kt = 0; kt < 4; ++kt) {
                union { unsigned long long u; __bf16 h4[4]; } pk;
                for (int r = 0; r < 4; ++r) pk.h4[r] = (__bf16)st[kt][r];
                *(unsigned long long*)&Ps[wid8][l16 * 64 + ((kt * 16 + quad * 4) ^ sw)] = pk.u;
            }
            asm volatile("s_waitcnt lgkmcnt(0)" ::: "memory");

            __builtin_amdgcn_s_setprio(1);
            for (int c = 0; c < 2; ++c) {
                int ko = (c * 32 + quad * 8) ^ sw;
                bfrag pf = *(const bfrag*)&Ps[wid8][l16 * 64 + ko];
                for (int dt = 0; dt < 4; ++dt) {
                    bfrag vf = *(const bfrag*)&Vts[(dt * 16 + l16) * 64 + ko];
                    o[dt] = MFMA(pf, vf, o[dt]);
                }
                o_l = MFMA(pf, onesf, o_l);        // denominator: row-sum of P
            }
            __builtin_amdgcn_s_setprio(0);
        }
    }

    // epilogue: normalize by o_l (same C-layout rows as o), write O
    for (int r = 0; r < 4; ++r) {
        float inv = 1.0f / o_l[r];
        size_t base = ((size_t)b * SEQ + qb * 64 + wid * 16 + quad * 4 + r) * D_MODEL
                    + (size_t)h * HD;
        for (int dt = 0; dt < 4; ++dt)
            O[base + dt * 16 + l16] = (__bf16)(o[dt][r] * inv);
    }
}

// ---------------------------------------------------------------------------
extern "C" void kernel_launch(void* const* d_in, const int* in_sizes, int n_in,
                              void* d_out, int out_size, void* d_ws, size_t ws_size,
                              hipStream_t stream)
{
    const float* x  = (const float*)d_in[0];
    const float* Wq = (const float*)d_in[1];
    const float* bq = (const float*)d_in[2];
    const float* Wk = (const float*)d_in[3];
    const float* bk = (const float*)d_in[4];
    const float* Wv = (const float*)d_in[5];
    const float* bv = (const float*)d_in[6];
    const float* Wo = (const float*)d_in[7];
    const float* bo = (const float*)d_in[8];

    __bf16* ws = (__bf16*)d_ws;
    const size_t M1 = 1024u * 1024u;
    __bf16* qkv    = ws;                      // Q @0, K @4M, Vt @8M (24 MB)
    __bf16* attn_o = ws + 12 * M1;            // 4M (8 MB)
    __bf16* Wt     = ws + 16 * M1;            // 4M (8 MB)
    __bf16* xb     = ws + 20 * M1;            // 4M (8 MB) -> 48 MB total

    const bool fast = ws_size >= (size_t)48 * 1024 * 1024;

    if (fast) {
        k_prep<<<dim3(16, 16, 5), 256, 0, stream>>>(x, Wq, Wk, Wv, Wo, Wt, xb);
        k_gemm128<0, true><<<dim3(8, 32, 3), 256, 0, stream>>>(
            xb, Wt, Wt + M1, Wt + 2 * M1, bq, bk, bv, qkv);
        k_attn<<<dim3(16, 16, 2), 512, 0, stream>>>(
            qkv, qkv + 4 * M1, qkv + 8 * M1, attn_o);
        k_gemm_out<<<dim3(8, 64), 256, 0, stream>>>(
            attn_o, Wt + 3 * M1, bo, (float*)d_out);
    } else {
        k_gemm128<0, false><<<dim3(8, 32, 3), 256, 0, stream>>>(
            x, Wq, Wk, Wv, bq, bk, bv, qkv);
        k_attn<<<dim3(16, 16, 2), 512, 0, stream>>>(
            qkv, qkv + 4 * M1, qkv + 8 * M1, attn_o);
        k_gemm128<1, false><<<dim3(8, 32, 1), 256, 0, stream>>>(
            attn_o, Wo, Wo, Wo, bo, bo, bo, (float*)d_out);
    }
}